// Round 1
// baseline (68.354 us; speedup 1.0000x reference)
//
#include <hip/hip_runtime.h>

// HQNN quanvolution, analytically collapsed.
//
// Heisenberg-picture derivation (DEPTH=1 circuit:
//   RX(w0)@q0, RX(w1)@q1, CNOT(2,3), CNOT(0,2), CNOT(0,3), RY(w2)@q0, RY(w3)@q3):
//   <Z0> = cos(w2)cos(w0)c0 - sin(w2)s0 s2
//   <Z1> = cos(w1)c1
//   <Z2> = cos(w0)c0 c2
//   <Z3> = cos(w3)cos(w0)c0 c2 c3 - sin(w3)s3
// where ck=cos(pi*pk), sk=sin(pi*pk) of the patch pixels
// p0=(i,j) p1=(i,j+1) p2=(i+1,j) p3=(i+1,j+1).
// (Embedding state is a real product state: <X>=sin t, <Z>=cos t, <Y>=0.)
// Feature layout for the linear head: feat = q*729 + fi*27 + fj.

#define HD 28
#define FD 27
#define NPATCH (FD * FD)   // 729
#define NOUT 10

__global__ __launch_bounds__(256)
void hqnn_fused(const float* __restrict__ x,
                const float* __restrict__ W,
                const float* __restrict__ bias,
                const float* __restrict__ wts,
                float* __restrict__ out)
{
    __shared__ float sc[HD * HD];
    __shared__ float ss[HD * HD];
    __shared__ float red[4][NOUT];

    const int b   = blockIdx.x;
    const int tid = threadIdx.x;

    // Circuit parameters (4 scalars; broadcast loads). cosf(0)=1, sinf(0)=0 exact.
    const float w0 = wts[0], w1 = wts[1], w2 = wts[2], w3 = wts[3];
    const float cw0 = cosf(w0);
    const float cw1 = cosf(w1);
    const float cw2 = cosf(w2), sw2 = sinf(w2);
    const float cw3 = cosf(w3), sw3 = sinf(w3);

    // Phase 1: stage per-pixel cos/sin(pi * x) in LDS.
    const float* xb = x + b * (HD * HD);
    for (int i = tid; i < HD * HD; i += 256) {
        float s, c;
        sincospif(xb[i], &s, &c);
        sc[i] = c;
        ss[i] = s;
    }
    __syncthreads();

    // Phase 2: patches -> evs -> fused dot with W rows.
    float acc[NOUT];
#pragma unroll
    for (int o = 0; o < NOUT; ++o) acc[o] = 0.f;

    for (int idx = tid; idx < NPATCH; idx += 256) {
        const int fi = idx / FD;
        const int fj = idx - fi * FD;
        const int p  = fi * HD + fj;

        const float c00 = sc[p];
        const float c01 = sc[p + 1];
        const float c10 = sc[p + HD];
        const float c11 = sc[p + HD + 1];
        const float s00 = ss[p];
        const float s10 = ss[p + HD];
        const float s11 = ss[p + HD + 1];

        const float ev0 = cw2 * cw0 * c00 - sw2 * s00 * s10;
        const float ev1 = cw1 * c01;
        const float ev2 = cw0 * c00 * c10;
        const float ev3 = cw3 * ev2 * c11 - sw3 * s11;

        const float* Wp = W + idx;
#pragma unroll
        for (int o = 0; o < NOUT; ++o) {
            const float* Wo = Wp + o * (4 * NPATCH);
            acc[o] += ev0 * Wo[0]
                    + ev1 * Wo[NPATCH]
                    + ev2 * Wo[2 * NPATCH]
                    + ev3 * Wo[3 * NPATCH];
        }
    }

    // Phase 3: block reduction (wave64 shuffle, then 4-wave LDS combine).
#pragma unroll
    for (int o = 0; o < NOUT; ++o) {
#pragma unroll
        for (int off = 32; off >= 1; off >>= 1)
            acc[o] += __shfl_down(acc[o], off, 64);
    }
    const int lane = tid & 63;
    const int wv   = tid >> 6;
    if (lane == 0) {
#pragma unroll
        for (int o = 0; o < NOUT; ++o) red[wv][o] = acc[o];
    }
    __syncthreads();
    if (tid < NOUT) {
        out[b * NOUT + tid] =
            red[0][tid] + red[1][tid] + red[2][tid] + red[3][tid] + bias[tid];
    }
}

extern "C" void kernel_launch(void* const* d_in, const int* in_sizes, int n_in,
                              void* d_out, int out_size, void* d_ws, size_t ws_size,
                              hipStream_t stream) {
    const float* x    = (const float*)d_in[0];   // (B,1,28,28)
    const float* W    = (const float*)d_in[1];   // (10, 2916)
    const float* bias = (const float*)d_in[2];   // (10,)
    const float* wts  = (const float*)d_in[3];   // (1,4)
    float* out = (float*)d_out;                  // (B,10)

    const int B = in_sizes[0] / (HD * HD);
    hqnn_fused<<<B, 256, 0, stream>>>(x, W, bias, wts, out);
}

// Round 2
// 66.754 us; speedup vs baseline: 1.0240x; 1.0240x over previous
//
#include <hip/hip_runtime.h>

// HQNN quanvolution, analytically collapsed (see R0 derivation):
//   <Z0> = cos(w2)cos(w0)c0 - sin(w2)s0 s2
//   <Z1> = cos(w1)c1
//   <Z2> = cos(w0)c0 c2
//   <Z3> = cos(w3)<Z2>c3 - sin(w3)s3
// ck=cos(pi*pk), sk=sin(pi*pk); patch pixels p0=(i,j) p1=(i,j+1) p2=(i+1,j) p3=(i+1,j+1).
// Feature order for the linear head: f = q*729 + fi*27 + fj.
//
// R1 structure: per-image block. Phase 1: sincospi(x) -> LDS. Phase 1.5:
// ev values staged FLAT in LDS in feature order, so Phase 2 is an aligned
// float4 x float4 dot against W rows (o*2916 is 16B-aligned, 2916 = 729*4
// exactly; the q-row straddle inside a float4 group is correct by
// construction). Phase 3: padded-LDS partial reduction (no 60-shuffle chain).

#define HD 28
#define FD 27
#define NPATCH 729
#define NF 2916          // 4 * 729, divisible by 4
#define NG (NF / 4)      // 729 float4 groups
#define NOUT 10
#define PSTR 257         // padded stride for partials (bank spread)

__global__ __launch_bounds__(256)
void hqnn_fused(const float* __restrict__ x,
                const float* __restrict__ W,
                const float* __restrict__ bias,
                const float* __restrict__ wts,
                float* __restrict__ out)
{
    __shared__ float sc[HD * HD];
    __shared__ float ss[HD * HD];
    __shared__ __align__(16) float evl[NF];
    __shared__ float part[NOUT * PSTR];

    const int b   = blockIdx.x;
    const int tid = threadIdx.x;

    // Circuit parameters (uniform; weights==0 at runtime -> cw=1, sw=0 exact).
    const float w0 = wts[0], w1 = wts[1], w2 = wts[2], w3 = wts[3];
    const float cw0 = cosf(w0);
    const float cw1 = cosf(w1);
    const float cw2 = cosf(w2), sw2 = sinf(w2);
    const float cw3 = cosf(w3), sw3 = sinf(w3);

    // Phase 1: sincospi of the image into LDS (784 px = 196 float4 loads).
    const float4* xb4 = (const float4*)(x + b * (HD * HD));
    if (tid < 196) {
        const float4 v = xb4[tid];
        float s0, c0, s1, c1, s2, c2, s3, c3;
        sincospif(v.x, &s0, &c0);
        sincospif(v.y, &s1, &c1);
        sincospif(v.z, &s2, &c2);
        sincospif(v.w, &s3, &c3);
        const int p4 = tid * 4;
        sc[p4] = c0; sc[p4 + 1] = c1; sc[p4 + 2] = c2; sc[p4 + 3] = c3;
        ss[p4] = s0; ss[p4 + 1] = s1; ss[p4 + 2] = s2; ss[p4 + 3] = s3;
    }
    __syncthreads();

    // Phase 1.5: ev values, stored flat in feature order f = q*729 + patch.
    for (int pp = tid; pp < NPATCH; pp += 256) {
        const int fi = pp / FD;
        const int fj = pp - fi * FD;
        const int p  = fi * HD + fj;

        const float c00 = sc[p];
        const float c01 = sc[p + 1];
        const float c10 = sc[p + HD];
        const float c11 = sc[p + HD + 1];
        const float s00 = ss[p];
        const float s10 = ss[p + HD];
        const float s11 = ss[p + HD + 1];

        const float ev2 = cw0 * c00 * c10;
        evl[pp]               = cw2 * cw0 * c00 - sw2 * s00 * s10;
        evl[NPATCH + pp]      = cw1 * c01;
        evl[2 * NPATCH + pp]  = ev2;
        evl[3 * NPATCH + pp]  = cw3 * ev2 * c11 - sw3 * s11;
    }
    __syncthreads();

    // Phase 2: aligned float4 dot against all 10 W rows.
    float acc[NOUT];
#pragma unroll
    for (int o = 0; o < NOUT; ++o) acc[o] = 0.f;

    const float4* W4  = (const float4*)W;
    const float4* ev4 = (const float4*)evl;
    for (int g = tid; g < NG; g += 256) {
        const float4 e = ev4[g];
#pragma unroll
        for (int o = 0; o < NOUT; ++o) {
            const float4 w = W4[o * NG + g];
            acc[o] += e.x * w.x + e.y * w.y + e.z * w.z + e.w * w.w;
        }
    }

    // Phase 3: LDS partial reduction. part[o][tid], padded stride.
#pragma unroll
    for (int o = 0; o < NOUT; ++o) part[o * PSTR + tid] = acc[o];
    __syncthreads();

    if (tid < NOUT * 16) {
        const int o = tid >> 4;
        const int j = tid & 15;
        float s = 0.f;
#pragma unroll
        for (int k = 0; k < 256; k += 16) s += part[o * PSTR + j + k];
        s += __shfl_down(s, 8, 16);
        s += __shfl_down(s, 4, 16);
        s += __shfl_down(s, 2, 16);
        s += __shfl_down(s, 1, 16);
        if (j == 0) out[b * NOUT + o] = s + bias[o];
    }
}

extern "C" void kernel_launch(void* const* d_in, const int* in_sizes, int n_in,
                              void* d_out, int out_size, void* d_ws, size_t ws_size,
                              hipStream_t stream) {
    const float* x    = (const float*)d_in[0];   // (B,1,28,28) f32
    const float* W    = (const float*)d_in[1];   // (10, 2916) f32
    const float* bias = (const float*)d_in[2];   // (10,) f32
    const float* wts  = (const float*)d_in[3];   // (1,4) f32 (zeros)
    float* out = (float*)d_out;                  // (B,10) f32

    const int B = in_sizes[0] / (HD * HD);
    hqnn_fused<<<B, 256, 0, stream>>>(x, W, bias, wts, out);
}

// Round 3
// 65.128 us; speedup vs baseline: 1.0495x; 1.0250x over previous
//
#include <hip/hip_runtime.h>

// HQNN quanvolution, analytically collapsed (Heisenberg picture, DEPTH=1):
//   <Z0> = cos(w2)cos(w0)c0 - sin(w2)s0 s2
//   <Z1> = cos(w1)c1
//   <Z2> = cos(w0)c0 c2
//   <Z3> = cos(w3)<Z2>c3 - sin(w3)s3
// ck=cos(pi*pk), sk=sin(pi*pk); patch pixels p0=(i,j) p1=(i,j+1) p2=(i+1,j)
// p3=(i+1,j+1). Feature order for the linear head: f = q*729 + fi*27 + fj.
//
// R2: 2 images per block (grid 512). The 10 W float4 loads per group
// iteration now feed 20 accumulator dots -> W L2 traffic and VMEM instr
// count halve vs R1. part[] overlays sc/ss via a union (both dead after
// the post-Phase-1.5 barrier) to keep LDS at ~44 KB -> 3 blocks/CU.

#define HD 28
#define NPIX 784          // 28*28
#define FD 27
#define NPATCH 729
#define NF 2916           // 4 * 729
#define NG 729            // float4 groups per W row
#define NOUT 10
#define PSTR 257          // padded stride for partials
#define IM 2              // images per block

__global__ __launch_bounds__(256)
void hqnn_fused(const float* __restrict__ x,
                const float* __restrict__ W,
                const float* __restrict__ bias,
                const float* __restrict__ wts,
                float* __restrict__ out)
{
    __shared__ __align__(16) float evl[IM][NF];
    __shared__ union U {
        struct { float sc[IM][NPIX]; float ss[IM][NPIX]; } tr;
        float part[IM * NOUT][PSTR];
    } u;

    const int tid = threadIdx.x;

    // Circuit parameters (uniform; weights==0 at runtime -> cw=1, sw=0 exact).
    const float w0 = wts[0], w1 = wts[1], w2 = wts[2], w3 = wts[3];
    const float cw0 = cosf(w0);
    const float cw1 = cosf(w1);
    const float cw2 = cosf(w2), sw2 = sinf(w2);
    const float cw3 = cosf(w3), sw3 = sinf(w3);

    // Phase 1: sincospi of both images into LDS (392 contiguous float4s).
    const float4* xb4 = (const float4*)(x + blockIdx.x * (IM * NPIX));
    for (int t = tid; t < IM * NPIX / 4; t += 256) {
        const float4 v = xb4[t];
        const int p4  = t * 4;
        const int img = (p4 >= NPIX) ? 1 : 0;   // IM == 2
        const int off = p4 - img * NPIX;
        float s0, c0, s1, c1, s2, c2, s3, c3;
        sincospif(v.x, &s0, &c0);
        sincospif(v.y, &s1, &c1);
        sincospif(v.z, &s2, &c2);
        sincospif(v.w, &s3, &c3);
        u.tr.sc[img][off]     = c0; u.tr.ss[img][off]     = s0;
        u.tr.sc[img][off + 1] = c1; u.tr.ss[img][off + 1] = s1;
        u.tr.sc[img][off + 2] = c2; u.tr.ss[img][off + 2] = s2;
        u.tr.sc[img][off + 3] = c3; u.tr.ss[img][off + 3] = s3;
    }
    __syncthreads();

    // Phase 1.5: ev values, flat in feature order f = q*729 + patch.
    for (int pp = tid; pp < IM * NPATCH; pp += 256) {
        const int img = pp / NPATCH;
        const int pa  = pp - img * NPATCH;
        const int fi  = pa / FD;
        const int fj  = pa - fi * FD;
        const int p   = fi * HD + fj;

        const float c00 = u.tr.sc[img][p];
        const float c01 = u.tr.sc[img][p + 1];
        const float c10 = u.tr.sc[img][p + HD];
        const float c11 = u.tr.sc[img][p + HD + 1];
        const float s00 = u.tr.ss[img][p];
        const float s10 = u.tr.ss[img][p + HD];
        const float s11 = u.tr.ss[img][p + HD + 1];

        const float ev2 = cw0 * c00 * c10;
        evl[img][pa]               = cw2 * cw0 * c00 - sw2 * s00 * s10;
        evl[img][NPATCH + pa]      = cw1 * c01;
        evl[img][2 * NPATCH + pa]  = ev2;
        evl[img][3 * NPATCH + pa]  = cw3 * ev2 * c11 - sw3 * s11;
    }
    __syncthreads();   // sc/ss dead from here; part may overlay them.

    // Phase 2: aligned float4 dots; 10 W loads feed 20 accumulators.
    float acc[IM][NOUT];
#pragma unroll
    for (int m = 0; m < IM; ++m)
#pragma unroll
        for (int o = 0; o < NOUT; ++o) acc[m][o] = 0.f;

    const float4* W4 = (const float4*)W;
    const float4* e0 = (const float4*)evl[0];
    const float4* e1 = (const float4*)evl[1];
    for (int g = tid; g < NG; g += 256) {
        const float4 a = e0[g];
        const float4 c = e1[g];
#pragma unroll
        for (int o = 0; o < NOUT; ++o) {
            const float4 w = W4[o * NG + g];
            acc[0][o] += a.x * w.x + a.y * w.y + a.z * w.z + a.w * w.w;
            acc[1][o] += c.x * w.x + c.y * w.y + c.z * w.z + c.w * w.w;
        }
    }

    // Phase 3: LDS partial reduction (part overlays sc/ss).
#pragma unroll
    for (int m = 0; m < IM; ++m)
#pragma unroll
        for (int o = 0; o < NOUT; ++o) u.part[m * NOUT + o][tid] = acc[m][o];
    __syncthreads();

    if (tid < IM * NOUT * 8) {          // 160 lanes: 20 rows x 8 lanes
        const int row = tid >> 3;
        const int j   = tid & 7;
        float s = 0.f;
#pragma unroll
        for (int k = 0; k < 256; k += 8) s += u.part[row][j + k];
        s += __shfl_down(s, 4, 8);
        s += __shfl_down(s, 2, 8);
        s += __shfl_down(s, 1, 8);
        if (j == 0) {
            const int img = (row >= NOUT) ? 1 : 0;
            const int o   = row - img * NOUT;
            out[(blockIdx.x * IM + img) * NOUT + o] = s + bias[o];
        }
    }
}

extern "C" void kernel_launch(void* const* d_in, const int* in_sizes, int n_in,
                              void* d_out, int out_size, void* d_ws, size_t ws_size,
                              hipStream_t stream) {
    const float* x    = (const float*)d_in[0];   // (B,1,28,28) f32
    const float* W    = (const float*)d_in[1];   // (10, 2916) f32
    const float* bias = (const float*)d_in[2];   // (10,) f32
    const float* wts  = (const float*)d_in[3];   // (1,4) f32 (zeros)
    float* out = (float*)d_out;                  // (B,10) f32

    const int B = in_sizes[0] / NPIX;            // 1024
    hqnn_fused<<<B / IM, 256, 0, stream>>>(x, W, bias, wts, out);
}